// Round 1
// baseline (140.392 us; speedup 1.0000x reference)
//
#include <hip/hip_runtime.h>
#include <hip/hip_bf16.h>

#define B_ 128
#define S_ 513
#define H_ 256

typedef __attribute__((ext_vector_type(8))) short short8;
typedef __attribute__((ext_vector_type(4))) float f32x4;

// fp32 -> bf16 round-to-nearest-even (matches hardware cvt semantics closely
// enough; NaN path irrelevant for this data)
static __device__ inline unsigned short f2bf(float f) {
    union { float f; unsigned int u; } v; v.f = f;
    unsigned int u = v.u;
    unsigned int r = u + 0x7fffu + ((u >> 16) & 1u);
    return (unsigned short)(r >> 16);
}

// One block = one (s, batch-half): M=64 rows of x (all sharing W[idx(s)]),
// N=256 (full out dim -- so x is read exactly once), K=256 in BK=64 tiles.
// 4 waves, each computing 64x64 via 4x4 tiles of mfma_f32_16x16x32_bf16.
__global__ __launch_bounds__(256, 3)
void sel_gemm_kernel(const float* __restrict__ x,
                     const float* __restrict__ W,
                     const float* __restrict__ bias,
                     float* __restrict__ out) {
    const int bx = blockIdx.x;
    const int s  = bx >> 1;        // 0..512
    const int h  = bx & 1;         // batch half
    const int m_idx = (s < 3) ? s : ((s & 1) ? 3 : 4);

    // +8 bf16 pad per row (144 B = 36 banks) -> fragment reads are ~2-way max
    __shared__ unsigned short As[64 * 72];
    __shared__ unsigned short Bs[256 * 72];

    const int t    = threadIdx.x;
    const int lane = t & 63;
    const int w    = t >> 6;       // wave id 0..3 (n-direction)
    const int lrow = lane & 15;
    const int quad = lane >> 4;

    const float* xbase = x + ((size_t)(h * 64) * S_ + s) * H_;
    const float* Wbase = W + (size_t)m_idx * H_ * H_;

    f32x4 acc[4][4];
#pragma unroll
    for (int i = 0; i < 4; ++i)
#pragma unroll
        for (int j = 0; j < 4; ++j) {
            f32x4 z = {0.f, 0.f, 0.f, 0.f};
            acc[i][j] = z;
        }

    for (int kt = 0; kt < 4; ++kt) {
        const int k0 = kt * 64;
        __syncthreads();

        // Stage A: 64 rows x 64 fp32 -> bf16 LDS. 1024 float4, 4/thread.
#pragma unroll
        for (int i = 0; i < 4; ++i) {
            int flat = i * 256 + t;
            int row  = flat >> 4;          // 0..63 (batch within half)
            int col  = (flat & 15) * 4;    // 0..60
            const float4 v = *(const float4*)(xbase + (size_t)row * (S_ * H_) + k0 + col);
            ushort4 p;
            p.x = f2bf(v.x); p.y = f2bf(v.y); p.z = f2bf(v.z); p.w = f2bf(v.w);
            *(ushort4*)&As[row * 72 + col] = p;
        }
        // Stage B: 256 rows(d) x 64 fp32 -> bf16 LDS. 4096 float4, 16/thread.
#pragma unroll 8
        for (int i = 0; i < 16; ++i) {
            int flat = i * 256 + t;
            int row  = flat >> 4;          // 0..255 (d)
            int col  = (flat & 15) * 4;
            const float4 v = *(const float4*)(Wbase + (size_t)row * H_ + k0 + col);
            ushort4 p;
            p.x = f2bf(v.x); p.y = f2bf(v.y); p.z = f2bf(v.z); p.w = f2bf(v.w);
            *(ushort4*)&Bs[row * 72 + col] = p;
        }
        __syncthreads();

        // Compute: 2 K-steps of 32 per BK=64 tile.
#pragma unroll
        for (int kk = 0; kk < 64; kk += 32) {
            const int kf = kk + quad * 8;
            short8 a_frag[4], b_frag[4];
#pragma unroll
            for (int i = 0; i < 4; ++i)
                a_frag[i] = *(const short8*)&As[(i * 16 + lrow) * 72 + kf];
#pragma unroll
            for (int j = 0; j < 4; ++j)
                b_frag[j] = *(const short8*)&Bs[(w * 64 + j * 16 + lrow) * 72 + kf];
#pragma unroll
            for (int i = 0; i < 4; ++i)
#pragma unroll
                for (int j = 0; j < 4; ++j)
                    acc[i][j] = __builtin_amdgcn_mfma_f32_16x16x32_bf16(
                        a_frag[i], b_frag[j], acc[i][j], 0, 0, 0);
        }
    }

    // Bias: sum of all 5 bias rows at each d this lane stores (L2-hit loads).
    float bsum[4];
#pragma unroll
    for (int j = 0; j < 4; ++j) {
        int d = w * 64 + j * 16 + lrow;
        float sum = 0.f;
#pragma unroll
        for (int i = 0; i < 5; ++i) sum += bias[i * H_ + d];
        bsum[j] = sum;
    }

    // Epilogue. C/D layout (verified m89/m91): col = lane&15, row = quad*4+reg.
#pragma unroll
    for (int i = 0; i < 4; ++i) {
#pragma unroll
        for (int r = 0; r < 4; ++r) {
            int bg = h * 64 + i * 16 + quad * 4 + r;   // global batch index
            float* orow = out + ((size_t)bg * S_ + s) * H_;
#pragma unroll
            for (int j = 0; j < 4; ++j) {
                int d = w * 64 + j * 16 + lrow;
                orow[d] = acc[i][j][r] + bsum[j];
            }
        }
    }
}

extern "C" void kernel_launch(void* const* d_in, const int* in_sizes, int n_in,
                              void* d_out, int out_size, void* d_ws, size_t ws_size,
                              hipStream_t stream) {
    const float* x    = (const float*)d_in[0];
    const float* W    = (const float*)d_in[1];
    const float* bias = (const float*)d_in[2];
    float* out = (float*)d_out;

    dim3 grid(S_ * 2);   // 513 positions x 2 batch halves
    dim3 block(256);
    sel_gemm_kernel<<<grid, block, 0, stream>>>(x, W, bias, out);
}